// Round 13
// baseline (164.248 us; speedup 1.0000x reference)
//
#include <hip/hip_runtime.h>
#include <math.h>

#define NROWS  65536   // 16*64*64 rows
#define D      64
#define K      1024
#define NCT    8       // code tiles (K / BC)
#define BR     128     // rows per block tile
#define BC     128     // codes per block tile
#define TM     8       // rows per thread (row = 16*i + ty)
#define TN     8       // codes per thread (code = 16*c + tx)
#define BETA   0.25f

// ---------------------------------------------------------------- enorm ----
__global__ __launch_bounds__(256) void vq_enorm(const float* __restrict__ emb,
                                                float* __restrict__ enorm) {
    int k = blockIdx.x * 256 + threadIdx.x;
    if (k >= K) return;
    const float4* e4 = (const float4*)(emb + (size_t)k * D);
    float s = 0.f;
    #pragma unroll
    for (int i = 0; i < 16; ++i) {
        float4 e = e4[i];
        s += e.x * e.x + e.y * e.y + e.z * e.z + e.w * e.w;
    }
    enorm[k] = s;
}

// ---------------------------------------------------------------- xnorm ----
// EXACT same summation order as the proven-passing kernels' xnorm.
__global__ __launch_bounds__(256) void vq_xnorm(const float* __restrict__ x,
                                                float* __restrict__ xn) {
    int n = blockIdx.x * 256 + threadIdx.x;
    const float4* xp = (const float4*)(x + (size_t)n * D);
    float s = 0.f;
    #pragma unroll
    for (int i = 0; i < 16; ++i) {
        float4 v = xp[i];
        s += v.x * v.x + v.y * v.y + v.z * v.z + v.w * v.w;
    }
    xn[n] = s;
}

// ----------------------------------------------------------------- main ----
// Register-tiled distance GEMM (same arithmetic as R10-R12, all PASSED).
// R13: instruction-stream slimming only (occupancy is pinned at ~2 blocks/CU
// by the register file regardless of launch_bounds; R12 proved that):
//  (a) LDS reads via hoisted per-k4 base + ds_read immediate offsets
//      (c*2048 / i*2048); address VALU ~70 -> ~4 instr per k4.
//  (b) epilogue: per-row f32 strict-< scan (c ascending = idx ascending,
//      ties -> lowest idx), ONE u64 pack per row, then 4-step __shfl_xor
//      width-16 u64-min butterfly. Removes the red[] LDS buffer, 2 barriers,
//      and the 128-thread serial scan. Exact same selection semantics.
__global__ __launch_bounds__(256) void vq_main(const float* __restrict__ x,
                                               const float* __restrict__ emb,
                                               const float* __restrict__ enorm,
                                               const float* __restrict__ xn,
                                               unsigned short* __restrict__ cand) {
    __shared__ float4 xS[BR * 8];              // 16 KB, slot = r*8 + (k4 ^ (r&7))
    __shared__ float4 eS[BC * 8];              // 16 KB, same swizzle
    __shared__ float  enl[BC];                 // 0.5 KB
    __shared__ float  xnl[BR];                 // 0.5 KB

    const int tid = threadIdx.x;
    const int tx  = tid & 15;
    const int ty  = tid >> 4;
    const int rb  = (int)(blockIdx.x >> 3) * BR;
    const int ct  = (int)(blockIdx.x & 7);
    const int cb  = ct * BC;

    if (tid < BC) enl[tid] = enorm[cb + tid];
    if (tid < BR) xnl[tid] = xn[rb + tid];

    float acc[TM][TN];
    #pragma unroll
    for (int i = 0; i < TM; ++i)
        #pragma unroll
        for (int c = 0; c < TN; ++c) acc[i][c] = 0.f;

    const float4* x4 = (const float4*)x;
    const float4* e4 = (const float4*)emb;

    // byte-offset XOR components; (k4^(tx&7))<<4 == (k4<<4) ^ xore
    const int xore = (tx & 7) << 4;
    const int xorx = (ty & 7) << 4;
    const char* eBase = (const char*)eS + tx * 128;
    const char* xBase = (const char*)xS + ty * 128;

    for (int s = 0; s < 2; ++s) {              // two 32-dim halves
        __syncthreads();
        // stage 128 rows x 8 float4 of x and e into swizzled slots.
        #pragma unroll
        for (int p = 0; p < 4; ++p) {
            int idx  = p * 256 + tid;          // 0..1023
            int r    = idx >> 3;
            int k4   = idx & 7;
            int slot = r * 8 + (k4 ^ (r & 7));
            xS[slot] = x4[(size_t)(rb + r) * 16 + s * 8 + k4];
            eS[slot] = e4[(size_t)(cb + r) * 16 + s * 8 + k4];
        }
        __syncthreads();

        #pragma unroll 2
        for (int k4 = 0; k4 < 8; ++k4) {
            const char* ep = eBase + ((k4 << 4) ^ xore);   // one v_xor/v_add
            const char* xp = xBase + ((k4 << 4) ^ xorx);
            float4 ev[TN];
            #pragma unroll
            for (int c = 0; c < TN; ++c)       // ds_read_b128 offset:c*2048
                ev[c] = *(const float4*)(ep + c * 2048);
            #pragma unroll
            for (int i = 0; i < TM; ++i) {     // ds_read_b128 offset:i*2048
                float4 xv = *(const float4*)(xp + i * 2048);
                #pragma unroll
                for (int c = 0; c < TN; ++c) { // k-sequential chain per (i,c)
                    acc[i][c] = fmaf(xv.x, ev[c].x, acc[i][c]);
                    acc[i][c] = fmaf(xv.y, ev[c].y, acc[i][c]);
                    acc[i][c] = fmaf(xv.z, ev[c].z, acc[i][c]);
                    acc[i][c] = fmaf(xv.w, ev[c].w, acc[i][c]);
                }
            }
        }
    }

    // epilogue: per-row argmin (same dist form/values as R10-R12)
    float env[TN];
    #pragma unroll
    for (int c = 0; c < TN; ++c) env[c] = enl[16 * c + tx];

    #pragma unroll
    for (int i = 0; i < TM; ++i) {
        const float xnr = xnl[16 * i + ty];
        float bd = 3.4e38f;
        int   bi = 0;
        #pragma unroll
        for (int c = 0; c < TN; ++c) {         // c ascending = idx ascending
            float d = fmaf(-2.f, acc[i][c], xnr + env[c]);  // same final op as R1
            if (d < bd) { bd = d; bi = cb + 16 * c + tx; }  // strict <
        }
        // pack (orderable dist, idx): u64 min == (min dist, then min idx)
        unsigned int b = __float_as_uint(bd);
        unsigned int u = (b & 0x80000000u) ? ~b : (b | 0x80000000u);
        unsigned long long v = ((unsigned long long)u << 32) | (unsigned int)bi;
        // exact u64-min butterfly across the 16 tx lanes of this row
        #pragma unroll
        for (int off = 8; off >= 1; off >>= 1) {
            unsigned long long o =
                (unsigned long long)__shfl_xor((long long)v, off, 16);
            if (o < v) v = o;
        }
        if (tx == 0)
            cand[(size_t)ct * NROWS + rb + 16 * i + ty] =
                (unsigned short)(v & 0xFFFFu);
    }
}

// ------------------------------------------- combine (exact re-eval) -------
// Verbatim the bench-PASSING combine: recomputes the NCT candidate dists
// with the proven 4-chain fmaf arithmetic; tiles scanned in ascending-k
// order with strict < -> exact argmin semantics.
__global__ __launch_bounds__(256) void vq_combine(const float* __restrict__ x,
                                                  const float* __restrict__ emb,
                                                  const float* __restrict__ enorm,
                                                  const unsigned short* __restrict__ cand,
                                                  float* __restrict__ out,
                                                  float* __restrict__ partial) {
    __shared__ float lds_red[256];

    const int tid = threadIdx.x;
    const int n   = blockIdx.x * 256 + tid;

    float4 xr[16];
    const float4* xp = (const float4*)(x + (size_t)n * D);
    #pragma unroll
    for (int i = 0; i < 16; ++i) xr[i] = xp[i];

    float xnorm = 0.f;
    #pragma unroll
    for (int i = 0; i < 16; ++i) {
        float4 v = xr[i];
        xnorm += v.x * v.x + v.y * v.y + v.z * v.z + v.w * v.w;
    }

    float best = 3.4e38f;
    int   bi   = 0;

    for (int s = 0; s < NCT; ++s) {
        int k = cand[(size_t)s * NROWS + n];           // per-lane gather
        const float4* e4 = (const float4*)(emb + (size_t)k * D);
        float d0 = 0.f, d1 = 0.f, d2 = 0.f, d3 = 0.f;
        #pragma unroll
        for (int i = 0; i < 4; ++i) {
            float4 ea = e4[i * 4 + 0], eb = e4[i * 4 + 1];
            float4 ec = e4[i * 4 + 2], ed = e4[i * 4 + 3];
            float4 va = xr[i * 4 + 0], vb = xr[i * 4 + 1];
            float4 vc = xr[i * 4 + 2], vd = xr[i * 4 + 3];
            d0 = fmaf(va.w, ea.w, fmaf(va.z, ea.z, fmaf(va.y, ea.y, fmaf(va.x, ea.x, d0))));
            d1 = fmaf(vb.w, eb.w, fmaf(vb.z, eb.z, fmaf(vb.y, eb.y, fmaf(vb.x, eb.x, d1))));
            d2 = fmaf(vc.w, ec.w, fmaf(vc.z, ec.z, fmaf(vc.y, ec.y, fmaf(vc.x, ec.x, d2))));
            d3 = fmaf(vd.w, ed.w, fmaf(vd.z, ed.z, fmaf(vd.y, ed.y, fmaf(vd.x, ed.x, d3))));
        }
        float dot  = (d0 + d1) + (d2 + d3);
        float dist = fmaf(-2.f, dot, xnorm + enorm[k]);
        if (dist < best) { best = dist; bi = k; }      // ascending k; strict <
    }

    // gather chosen row, write output, accumulate squared error
    const float4* q4 = (const float4*)(emb + (size_t)bi * D);
    float4* o4 = (float4*)(out + (size_t)n * D);
    float err = 0.f;
    #pragma unroll
    for (int i = 0; i < 16; ++i) {
        float4 q = q4[i];
        float4 v = xr[i];
        float ax = q.x - v.x, ay = q.y - v.y, az = q.z - v.z, aw = q.w - v.w;
        err += ax * ax + ay * ay + az * az + aw * aw;
        o4[i] = q;
    }

    __syncthreads();
    lds_red[tid] = err;
    __syncthreads();
    for (int s = 128; s > 0; s >>= 1) {
        if (tid < s) lds_red[tid] += lds_red[tid + s];
        __syncthreads();
    }
    if (tid == 0) partial[blockIdx.x] = lds_red[0];
}

// ------------------------------------------------------------- finalize ----
__global__ __launch_bounds__(256) void vq_finish(const float* __restrict__ partial,
                                                 float* __restrict__ loss_out) {
    __shared__ float lds[256];
    int tid = threadIdx.x;
    lds[tid] = partial[tid];
    __syncthreads();
    for (int s = 128; s > 0; s >>= 1) {
        if (tid < s) lds[tid] += lds[tid + s];
        __syncthreads();
    }
    // loss = codebook + BETA*commitment = (1+BETA) * mean((q-x)^2)
    if (tid == 0) loss_out[0] = (1.0f + BETA) * lds[0] / (float)(NROWS * D);
}

// ---------------------------------------------------------------- launch ---
extern "C" void kernel_launch(void* const* d_in, const int* in_sizes, int n_in,
                              void* d_out, int out_size, void* d_ws, size_t ws_size,
                              hipStream_t stream) {
    const float* x   = (const float*)d_in[0];
    const float* emb = (const float*)d_in[1];
    float* out = (float*)d_out;

    float* enorm   = (float*)d_ws;                         // K floats (4 KB)
    float* partial = enorm + K;                            // 256 floats
    float* xnbuf   = (float*)((char*)d_ws + 8192);         // NROWS floats (256 KB)
    unsigned short* cand =
        (unsigned short*)((char*)d_ws + 8192 + NROWS * 4); // NCT*NROWS u16 (1 MB)

    vq_enorm<<<K / 256, 256, 0, stream>>>(emb, enorm);
    vq_xnorm<<<NROWS / 256, 256, 0, stream>>>(x, xnbuf);
    vq_main<<<(NROWS / BR) * NCT, 256, 0, stream>>>(x, emb, enorm, xnbuf, cand);
    vq_combine<<<NROWS / 256, 256, 0, stream>>>(x, emb, enorm, cand, out, partial);
    vq_finish<<<1, 256, 0, stream>>>(partial, out + (size_t)NROWS * D);
}

// Round 15
// 103.307 us; speedup vs baseline: 1.5899x; 1.5899x over previous
//
#include <hip/hip_runtime.h>
#include <math.h>

#define NROWS 65536
#define D     64
#define K     1024
#define NCT   8            // code tiles (K/128)
#define BR    128
#define BC    128
#define BETA  0.25f
#define SCALE 1024.0f      // pow2 -> exact f32 scaling; keeps xl/el f16-normal
#define THR   200.0f       // scaled-dist margin (~1.9e-4 unscaled; ~40x filter err)

typedef _Float16 half8  __attribute__((ext_vector_type(8)));
typedef float    f32x4  __attribute__((ext_vector_type(4)));

// ws layout (bytes) -- total < 800 KB (R14 lesson: keep well under proven ws)
#define WS_BP   0u                         // f16 [K][128]: cols 0-63 eh, 64-127 el (256 KB)
#define WS_EN   (256u*1024)                // f32 [K] (4 KB)
#define WS_FID  (WS_EN + 4u*1024)          // u32 [NROWS] (256 KB)
#define WS_LIST (WS_FID + 256u*1024)       // u32 [NROWS] (256 KB)
#define WS_CNT  (WS_LIST + 256u*1024)      // u32 counter (pad 256)
#define WS_PART (WS_CNT + 256u)            // f32 [256]

static __device__ __forceinline__ unsigned ordf(float f) {
    unsigned b = __float_as_uint(f);
    return (b & 0x80000000u) ? ~b : (b | 0x80000000u);
}
static __device__ __forceinline__ float unordf(unsigned u) {
    unsigned b = (u & 0x80000000u) ? (u & 0x7FFFFFFFu) : ~u;
    return __uint_as_float(b);
}

// ---------------------------------------------------- prep: enorm + packed B
__global__ __launch_bounds__(256) void vq_prep(const float* __restrict__ emb,
                                               float* __restrict__ enorm,
                                               _Float16* __restrict__ Bp,
                                               unsigned* __restrict__ counter) {
    if (blockIdx.x == 0 && threadIdx.x == 0) counter[0] = 0u;   // fresh each launch
    int k = blockIdx.x * 256 + threadIdx.x;
    if (k >= K) return;
    const float4* e4 = (const float4*)(emb + (size_t)k * D);
    _Float16* bp = Bp + (size_t)k * 128;
    float s = 0.f;
    #pragma unroll
    for (int i = 0; i < 16; ++i) {
        float4 e = e4[i];
        s += e.x * e.x + e.y * e.y + e.z * e.z + e.w * e.w;   // R1-order enorm
        float c0 = e.x * SCALE, c1 = e.y * SCALE, c2 = e.z * SCALE, c3 = e.w * SCALE;
        _Float16 h0 = (_Float16)c0, h1 = (_Float16)c1, h2 = (_Float16)c2, h3 = (_Float16)c3;
        bp[i*4+0] = h0; bp[64+i*4+0] = (_Float16)(c0 - (float)h0);
        bp[i*4+1] = h1; bp[64+i*4+1] = (_Float16)(c1 - (float)h1);
        bp[i*4+2] = h2; bp[64+i*4+2] = (_Float16)(c2 - (float)h2);
        bp[i*4+3] = h3; bp[64+i*4+3] = (_Float16)(c3 - (float)h3);
    }
    enorm[k] = s;
}

// ---------------------------- fused MFMA filter: all 8 code tiles per block
// dot ~ xh*eh + xh*el + xl*eh (f16 operands, f32 MFMA accum), dists reduced
// (xn drops per-row), running top-2 in registers across tiles, margin test
// at the end. 4 waves; wave = 32 rows x 128 cols (2x8 16x16x32 fragments).
// LDS rows padded to 72 f16 (144 B): b128 frag reads are bank-balanced.
__global__ __launch_bounds__(256, 2) void vq_gemm(const float* __restrict__ x,
                                                  const _Float16* __restrict__ Bp,
                                                  const float* __restrict__ enorm,
                                                  unsigned* __restrict__ fid,
                                                  unsigned* __restrict__ list,
                                                  unsigned* __restrict__ counter) {
    __shared__ _Float16 aSh[BR][72];           // 18.4 KB each
    __shared__ _Float16 aSl[BR][72];
    __shared__ _Float16 bSh[BC][72];
    __shared__ _Float16 bSl[BC][72];
    __shared__ float    en2[BC];

    const int tid = threadIdx.x;
    const int rb  = (int)blockIdx.x * BR;

    // stage A = xh | xl (once)
    const float4* x4 = (const float4*)x;
    #pragma unroll
    for (int p = 0; p < 8; ++p) {
        int q = p * 256 + tid;                 // 0..2047
        int r = q >> 4, c4 = q & 15;
        float4 v = x4[(size_t)(rb + r) * 16 + c4];
        float s0 = v.x * SCALE, s1 = v.y * SCALE, s2 = v.z * SCALE, s3 = v.w * SCALE;
        _Float16 h0 = (_Float16)s0, h1 = (_Float16)s1, h2 = (_Float16)s2, h3 = (_Float16)s3;
        aSh[r][c4*4+0] = h0;  aSl[r][c4*4+0] = (_Float16)(s0 - (float)h0);
        aSh[r][c4*4+1] = h1;  aSl[r][c4*4+1] = (_Float16)(s1 - (float)h1);
        aSh[r][c4*4+2] = h2;  aSl[r][c4*4+2] = (_Float16)(s2 - (float)h2);
        aSh[r][c4*4+3] = h3;  aSl[r][c4*4+3] = (_Float16)(s3 - (float)h3);
    }

    const int lane = tid & 63, w = tid >> 6;
    const int m0 = w * 32;                     // wave row base in tile
    const int fr = lane & 15;                  // frag row (A) / frag col (B)
    const int kg = lane >> 4;                  // k-group 0..3

    unsigned long long b1[2][4], b2[2][4];     // running top-2 per (fi,reg)
    #pragma unroll
    for (int fi = 0; fi < 2; ++fi)
        #pragma unroll
        for (int rg = 0; rg < 4; ++rg) { b1[fi][rg] = ~0ull; b2[fi][rg] = ~0ull; }

    const unsigned long long* bp64 = (const unsigned long long*)Bp;

    for (int ct = 0; ct < NCT; ++ct) {
        const int cb = ct * BC;
        __syncthreads();                       // protect b-buffers reuse
        // stage B: rows are 32 u64 (256 B) each -- FIXED stride (R14 bug: 16)
        #pragma unroll
        for (int p = 0; p < 16; ++p) {
            int q = p * 256 + tid;             // 0..4095
            int r = q >> 5, c = q & 31;
            unsigned long long v = bp64[(size_t)(cb + r) * 32 + c];
            if (c < 16) *(unsigned long long*)&bSh[r][c * 4] = v;
            else        *(unsigned long long*)&bSl[r][(c - 16) * 4] = v;
        }
        if (tid < BC) en2[tid] = enorm[cb + tid] * (SCALE * SCALE);  // pow2: exact
        __syncthreads();

        f32x4 acc[2][8];
        #pragma unroll
        for (int fi = 0; fi < 2; ++fi)
            #pragma unroll
            for (int ci = 0; ci < 8; ++ci) acc[fi][ci] = (f32x4){0.f, 0.f, 0.f, 0.f};

        auto CHUNK = [&](const _Float16 (*A)[72], const _Float16 (*B)[72]) {
            #pragma unroll
            for (int kk = 0; kk < 2; ++kk) {
                half8 a0 = *(const half8*)&A[m0 + fr][kk * 32 + kg * 8];
                half8 a1 = *(const half8*)&A[m0 + 16 + fr][kk * 32 + kg * 8];
                #pragma unroll
                for (int ci = 0; ci < 8; ++ci) {
                    half8 b = *(const half8*)&B[ci * 16 + fr][kk * 32 + kg * 8];
                    acc[0][ci] = __builtin_amdgcn_mfma_f32_16x16x32_f16(a0, b, acc[0][ci], 0, 0, 0);
                    acc[1][ci] = __builtin_amdgcn_mfma_f32_16x16x32_f16(a1, b, acc[1][ci], 0, 0, 0);
                }
            }
        };
        CHUNK(aSh, bSh);                       // xh * eh
        CHUNK(aSh, bSl);                       // xh * el
        CHUNK(aSl, bSh);                       // xl * eh

        // running top-2 update; ci ascending = idx ascending (tie -> low idx)
        #pragma unroll
        for (int fi = 0; fi < 2; ++fi) {
            #pragma unroll
            for (int rg = 0; rg < 4; ++rg) {
                #pragma unroll
                for (int ci = 0; ci < 8; ++ci) {
                    float r = fmaf(-2.f, acc[fi][ci][rg], en2[ci * 16 + fr]);
                    unsigned long long pk = ((unsigned long long)ordf(r) << 32)
                                          | (unsigned)(cb + ci * 16 + fr);
                    if (pk < b1[fi][rg])      { b2[fi][rg] = b1[fi][rg]; b1[fi][rg] = pk; }
                    else if (pk < b2[fi][rg]) { b2[fi][rg] = pk; }
                }
            }
        }
    }

    // final: butterfly top-2 across the 16 fr lanes, margin test, write
    #pragma unroll
    for (int fi = 0; fi < 2; ++fi) {
        #pragma unroll
        for (int rg = 0; rg < 4; ++rg) {
            unsigned long long v1 = b1[fi][rg], v2 = b2[fi][rg];
            #pragma unroll
            for (int off = 8; off >= 1; off >>= 1) {
                unsigned long long o1 = (unsigned long long)__shfl_xor((long long)v1, off, 16);
                unsigned long long o2 = (unsigned long long)__shfl_xor((long long)v2, off, 16);
                unsigned long long n1 = v1 < o1 ? v1 : o1;
                unsigned long long hi = v1 < o1 ? o1 : v1;
                unsigned long long n2 = o2 < v2 ? o2 : v2;
                if (hi < n2) n2 = hi;
                v1 = n1; v2 = n2;
            }
            if (fr == 0) {
                int row = rb + m0 + fi * 16 + kg * 4 + rg;
                float f1 = unordf((unsigned)(v1 >> 32));
                float f2 = unordf((unsigned)(v2 >> 32));
                if (f2 - f1 > THR) {
                    fid[row] = (unsigned)(v1 & 0xFFFFFFFFu);  // provably ref argmin
                } else {
                    unsigned pos = atomicAdd(counter, 1u);
                    list[pos] = (unsigned)row;
                }
            }
        }
    }
}

// --------------------------- exact fallback: full 1024-code scan, R1 form ---
__global__ __launch_bounds__(256) void vq_fallback(const float* __restrict__ x,
                                                   const float* __restrict__ emb,
                                                   const float* __restrict__ enorm,
                                                   const unsigned* __restrict__ list,
                                                   const unsigned* __restrict__ counter,
                                                   unsigned* __restrict__ final_idx) {
    __shared__ float4 xr[16];
    __shared__ unsigned long long red[256];
    const int tid = threadIdx.x;
    const unsigned total = counter[0];
    for (unsigned i = blockIdx.x; i < total; i += gridDim.x) {
        const int n = (int)list[i];
        __syncthreads();
        if (tid < 16) xr[tid] = ((const float4*)x)[(size_t)n * 16 + tid];
        __syncthreads();
        float xnorm = 0.f;                     // R1-order xnorm
        #pragma unroll
        for (int q = 0; q < 16; ++q) {
            float4 v = xr[q];
            xnorm += v.x * v.x + v.y * v.y + v.z * v.z + v.w * v.w;
        }
        unsigned long long best = ~0ull;
        #pragma unroll
        for (int j = 0; j < 4; ++j) {
            int k = tid + j * 256;
            const float4* e4 = (const float4*)(emb + (size_t)k * D);
            float d0 = 0.f, d1 = 0.f, d2 = 0.f, d3 = 0.f;
            #pragma unroll
            for (int q = 0; q < 4; ++q) {      // proven R1 4-chain ordering
                float4 ea = e4[q*4+0], eb = e4[q*4+1], ec = e4[q*4+2], ed = e4[q*4+3];
                float4 va = xr[q*4+0], vb = xr[q*4+1], vc = xr[q*4+2], vd = xr[q*4+3];
                d0 = fmaf(va.w, ea.w, fmaf(va.z, ea.z, fmaf(va.y, ea.y, fmaf(va.x, ea.x, d0))));
                d1 = fmaf(vb.w, eb.w, fmaf(vb.z, eb.z, fmaf(vb.y, eb.y, fmaf(vb.x, eb.x, d1))));
                d2 = fmaf(vc.w, ec.w, fmaf(vc.z, ec.z, fmaf(vc.y, ec.y, fmaf(vc.x, ec.x, d2))));
                d3 = fmaf(vd.w, ed.w, fmaf(vd.z, ed.z, fmaf(vd.y, ed.y, fmaf(vd.x, ed.x, d3))));
            }
            float dot  = (d0 + d1) + (d2 + d3);
            float dist = fmaf(-2.f, dot, xnorm + enorm[k]);
            unsigned long long pk = ((unsigned long long)ordf(dist) << 32) | (unsigned)k;
            if (pk < best) best = pk;          // dist-then-lowest-idx
        }
        red[tid] = best;
        __syncthreads();
        for (int s = 128; s > 0; s >>= 1) {
            if (tid < s) red[tid] = red[tid] < red[tid+s] ? red[tid] : red[tid+s];
            __syncthreads();
        }
        if (tid == 0) final_idx[n] = (unsigned)(red[0] & 0xFFFFFFFFu);
    }
}

// ------------------------------------------------------ gather + loss ------
__global__ __launch_bounds__(256) void vq_out(const float* __restrict__ x,
                                              const float* __restrict__ emb,
                                              const unsigned* __restrict__ final_idx,
                                              float* __restrict__ out,
                                              float* __restrict__ partial) {
    __shared__ int   lds_idx[256];
    __shared__ float lds_red[256];
    const int tid   = threadIdx.x;
    const int rbase = blockIdx.x * 256;
    const int n     = rbase + tid;

    lds_idx[tid] = (int)(final_idx[n] & 0xFFFFu);
    __syncthreads();

    const float4* x4 = (const float4*)x;
    const float4* e4 = (const float4*)emb;
    float4* o4 = (float4*)out;
    float err = 0.f;
    #pragma unroll
    for (int i = 0; i < 16; ++i) {
        int f = i * 256 + tid;
        int row = f >> 4, col = f & 15;
        int e = lds_idx[row];
        float4 q = e4[(size_t)e * 16 + col];
        float4 v = x4[(size_t)rbase * 16 + f];
        float ax = q.x - v.x, ay = q.y - v.y, az = q.z - v.z, aw = q.w - v.w;
        err += ax * ax + ay * ay + az * az + aw * aw;
        o4[(size_t)rbase * 16 + f] = q;
    }
    __syncthreads();
    lds_red[tid] = err;
    __syncthreads();
    for (int s = 128; s > 0; s >>= 1) {
        if (tid < s) lds_red[tid] += lds_red[tid + s];
        __syncthreads();
    }
    if (tid == 0) partial[blockIdx.x] = lds_red[0];
}

// ------------------------------------------------------------- finalize ----
__global__ __launch_bounds__(256) void vq_finish(const float* __restrict__ partial,
                                                 float* __restrict__ loss_out) {
    __shared__ float lds[256];
    int tid = threadIdx.x;
    lds[tid] = partial[tid];
    __syncthreads();
    for (int s = 128; s > 0; s >>= 1) {
        if (tid < s) lds[tid] += lds[tid + s];
        __syncthreads();
    }
    if (tid == 0) loss_out[0] = (1.0f + BETA) * lds[0] / (float)(NROWS * D);
}

// ---------------------------------------------------------------- launch ---
extern "C" void kernel_launch(void* const* d_in, const int* in_sizes, int n_in,
                              void* d_out, int out_size, void* d_ws, size_t ws_size,
                              hipStream_t stream) {
    const float* x   = (const float*)d_in[0];
    const float* emb = (const float*)d_in[1];
    float* out = (float*)d_out;
    char* ws = (char*)d_ws;

    _Float16* Bp      = (_Float16*)(ws + WS_BP);
    float* enorm      = (float*)(ws + WS_EN);
    unsigned* fid     = (unsigned*)(ws + WS_FID);
    unsigned* list    = (unsigned*)(ws + WS_LIST);
    unsigned* counter = (unsigned*)(ws + WS_CNT);
    float* partial    = (float*)(ws + WS_PART);

    vq_prep<<<K / 256, 256, 0, stream>>>(emb, enorm, Bp, counter);
    vq_gemm<<<NROWS / BR, 256, 0, stream>>>(x, Bp, enorm, fid, list, counter);
    vq_fallback<<<128, 256, 0, stream>>>(x, emb, enorm, list, counter, fid);
    vq_out<<<NROWS / 256, 256, 0, stream>>>(x, emb, fid, out, partial);
    vq_finish<<<1, 256, 0, stream>>>(partial, out + (size_t)NROWS * D);
}